// Round 8
// baseline (252.777 us; speedup 1.0000x reference)
//
#include <hip/hip_runtime.h>

#define HW 56
#define NPIX 3136          // 56*56
#define CIN 256
#define OUTC 256

typedef unsigned short ushort_t;
typedef unsigned int uint_t;

__device__ __forceinline__ float b2f(ushort_t u){ return __uint_as_float(((uint_t)u)<<16); }
__device__ __forceinline__ float blo(uint_t u){ return __uint_as_float(u<<16); }
__device__ __forceinline__ float bhi(uint_t u){ return __uint_as_float(u & 0xffff0000u); }
__device__ __forceinline__ ushort_t f2b(float f){
  uint_t u = __float_as_uint(f);
  u += 0x7fffu + ((u>>16)&1u);
  return (ushort_t)(u>>16);
}
__device__ __forceinline__ uint_t pack2(float lo, float hi){
  return ((uint_t)f2b(hi)<<16) | (uint_t)f2b(lo);
}
__device__ __forceinline__ int refl(int v){ v = v<0 ? -v : v; return v>=HW ? 2*HW-2-v : v; }

// ---- workspace layout (float element offsets unless noted) ----
#define WT_OFF   0          // Wt[256][288] fp32 (transposed proj weights, rows=cin)
#define BF_OFF   73728      // bias[288] (pad to 320)
#define CW1_OFF  74048      // cw1[16][16]
#define CW2_OFF  74304      // cw2[32][16]
#define CW2B_OFF 74816      // cw2b[32] (pad 64)
#define BNC_OFF  74880      // bn1s[16] bn1b[16] bn2s[16] bn2b[16]
#define P2T_OFF  74944      // P2t[57][256] = 14592, P2t[i][g*8+o] = p2[g][o][i]
#define X1T_OFF  89600      // x1t[4][3136][16] fp32 (pixel-major)
#define X2T_OFF  290304     // x2t[4][3136][16] fp32 (pixel-major)
#define X3_BYTE_OFF 1964032 // x3b[4][3136][256] bf16 (6,422,528 B) -> total ws = 8,386,560 B

// ===================== K0: weight prep (fp32 inputs) =====================
__global__ void k0_prep(const float* __restrict__ w1, const float* __restrict__ b1,
                        const float* __restrict__ w2, const float* __restrict__ b2,
                        const float* __restrict__ w3, const float* __restrict__ b3,
                        const float* __restrict__ g1, const float* __restrict__ be1,
                        const float* __restrict__ m1, const float* __restrict__ v1,
                        const float* __restrict__ cw1,
                        const float* __restrict__ g2, const float* __restrict__ be2,
                        const float* __restrict__ m2, const float* __restrict__ v2,
                        const float* __restrict__ cw2, const float* __restrict__ cw2b,
                        const float* __restrict__ p2,
                        float* __restrict__ ws)
{
  int idx = blockIdx.x*256 + threadIdx.x;
  if (idx < 73728){                       // Wt[c][r] = W[r][c]
    int c = idx / 288, r = idx - c*288;
    float v;
    if (r < 16)      v = w1[r*256 + c];
    else if (r < 32) v = w2[(r-16)*256 + c];
    else             v = w3[(r-32)*256 + c];
    ws[WT_OFF + idx] = v;
    return;
  }
  int j = idx - 73728;
  if (j < 288){ ws[BF_OFF+j] = (j<16 ? b1[j] : (j<32 ? b2[j-16] : b3[j-32])); return; }
  j -= 288;
  if (j < 256){ ws[CW1_OFF+j] = cw1[j]; return; }
  j -= 256;
  if (j < 512){ ws[CW2_OFF+j] = cw2[j]; return; }
  j -= 512;
  if (j < 32){ ws[CW2B_OFF+j] = cw2b[j]; return; }
  j -= 32;
  if (j < 64){
    int set = j >> 4, c = j & 15;
    float o;
    if (set == 0){ o = g1[c] * rsqrtf(v1[c] + 1e-5f); }
    else if (set == 1){ float s = g1[c] * rsqrtf(v1[c] + 1e-5f); o = be1[c] - m1[c]*s; }
    else if (set == 2){ o = g2[c] * rsqrtf(v2[c] + 1e-5f); }
    else { float s = g2[c] * rsqrtf(v2[c] + 1e-5f); o = be2[c] - m2[c]*s; }
    ws[BNC_OFF+j] = o;
    return;
  }
  j -= 64;
  if (j < 14592){                          // P2t[i][g*8+o] = p2[(g*8+o)*57 + i]
    int i = j >> 8, rem = j & 255;
    ws[P2T_OFF + j] = p2[rem*57 + i];
    return;
  }
}

// ===================== K1 v3: projection via LDS-staged x =====================
// 196 chunks (64 px) x 2 oc-halves = 392 blocks, 4 waves.
// Stage x[256][64] fp32 (64 KB) ONCE via global_load_lds; each wave computes 36 oc.
// Kills the 18x re-read (231 MB L2 traffic -> 25.7 MB) that pinned k1 at ~58-68 us.
__global__ __launch_bounds__(256,2) void k1_proj(const float* __restrict__ x,
                                                 float* __restrict__ ws,
                                                 ushort_t* __restrict__ x3b)
{
  __shared__ float xs[CIN*64];        // [c][px] fp32, 64 KB
  int t = threadIdx.x;
  int bid = blockIdx.x;
  int chunk = bid >> 1, bo = bid & 1;
  int b = chunk / 49, pp = (chunk - b*49)*64;
  int wv = __builtin_amdgcn_readfirstlane(t >> 6);
  int lane = t & 63;

  // ---- stage: 16 x global_load_lds(16B); LDS dest linear in thread order ----
  // thread t, iter i: c = i*16 + t/16, px = (t&15)*4 ; lds float idx = i*1024 + t*4 == c*64+px
  {
    const float* src = x + (size_t)b*CIN*NPIX + pp;
    int c0 = t >> 4;
    int po = (t & 15) * 4;
    #pragma unroll
    for (int i=0;i<16;i++){
      const float* gp = src + (size_t)(i*16 + c0)*NPIX + po;
      __builtin_amdgcn_global_load_lds(
          (const __attribute__((address_space(1))) void*)gp,
          (__attribute__((address_space(3))) void*)(xs + i*1024 + wv*256),
          16, 0, 0);
    }
  }
  __syncthreads();   // includes vmcnt(0) drain of the LDS-bound loads

  // ---- compute: wave wv covers oc [bo*144 + wv*36, +36) over 64 px ----
  int oc0 = bo*144 + wv*36;
  const float* Wt = ws + WT_OFF;
  float acc[36];
  #pragma unroll
  for (int j=0;j<36;j++) acc[j] = ws[BF_OFF + oc0 + j];
  #pragma unroll 1
  for (int cc=0; cc<CIN; cc+=8){
    float xv[8];
    #pragma unroll
    for (int u=0;u<8;u++) xv[u] = xs[(cc+u)*64 + lane];   // stride-1 lanes: 2-way alias, free
    #pragma unroll
    for (int u=0;u<8;u++){
      #pragma unroll
      for (int j=0;j<36;j++) acc[j] += xv[u] * Wt[(cc+u)*288 + oc0 + j];  // uniform -> s_load
    }
  }

  // ---- stores ----
  int sp = pp + lane;
  if (bo == 0 && wv == 0){
    float4* x1o = (float4*)(ws + X1T_OFF + (size_t)(b*NPIX+sp)*16);
    x1o[0] = make_float4(acc[0],acc[1],acc[2],acc[3]);
    x1o[1] = make_float4(acc[4],acc[5],acc[6],acc[7]);
    x1o[2] = make_float4(acc[8],acc[9],acc[10],acc[11]);
    x1o[3] = make_float4(acc[12],acc[13],acc[14],acc[15]);
    float4* x2o = (float4*)(ws + X2T_OFF + (size_t)(b*NPIX+sp)*16);
    x2o[0] = make_float4(acc[16],acc[17],acc[18],acc[19]);
    x2o[1] = make_float4(acc[20],acc[21],acc[22],acc[23]);
    x2o[2] = make_float4(acc[24],acc[25],acc[26],acc[27]);
    x2o[3] = make_float4(acc[28],acc[29],acc[30],acc[31]);
    // x3 channels 0..3
    uint2 d = make_uint2(pack2(acc[32],acc[33]), pack2(acc[34],acc[35]));
    *(uint2*)(x3b + ((size_t)b*NPIX + sp)*256) = d;          // 512B-aligned base
  } else {
    int cstart = oc0 - 32;                                    // 4,40,76,112,148,184,220 (even)
    ushort_t* dst = x3b + ((size_t)b*NPIX + sp)*256 + cstart; // byte off 8-aligned
    #pragma unroll
    for (int j2=0;j2<9;j2++){
      uint2 d = make_uint2(pack2(acc[j2*4],  acc[j2*4+1]),
                           pack2(acc[j2*4+2],acc[j2*4+3]));
      *(uint2*)(dst + j2*4) = d;
    }
  }
}

// ===================== K2: fused attention, wave-per-pixel =====================
// block = 4 waves = 4 consecutive x-pixels (same row); no x2/x3 LDS staging (L2-hot)
// XCD swizzle: 3136 blocks = 8 x 392 -> each XCD gets a contiguous half-image span
#define WST 33              // w_s row stride (floats)
__global__ __launch_bounds__(256,5) void k2_fused(const float* __restrict__ ws,
                                                  const ushort_t* __restrict__ x3b,
                                                  float* __restrict__ out)
{
  __shared__ float w_s[4*49*WST + 4];   // per-wave [49][32] (stride 33), unnormalized exp
  __shared__ __align__(16) float ags[4*256];
  __shared__ float invs[4*32];

  int tid = threadIdx.x;
  int bid0 = blockIdx.x;
  int bid = (bid0 & 7)*392 + (bid0 >> 3);     // XCD-contiguous pixel spans
  int b = bid / 784; int rem = bid - b*784;
  int row = rem / 14, xs4 = rem - row*14;
  int wv = __builtin_amdgcn_readfirstlane(tid >> 6);
  int lane = tid & 63;
  int y = row, x = xs4*4 + wv;
  int pix = y*HW + x;

  const float* bnc  = ws + BNC_OFF;
  const float* cw1  = ws + CW1_OFF;
  const float* cw2  = ws + CW2_OFF;
  const float* cw2b = ws + CW2B_OFF;
  float* wp = w_s + wv*49*WST;

  // ---- phase 1: per-tap MLP (lane = tap) ----
  {
    int k = lane;
    int kk = k < 49 ? k : 48;
    int ki = kk / 7, kj = kk - ki*7;
    int gy = refl(y + ki - 3), gx = refl(x + kj - 3);
    int go = gy*HW + gx;

    const float*  x1p = ws + X1T_OFF + (size_t)(b*NPIX + pix)*16;   // uniform -> s_load
    const float4* x2p = (const float4*)(ws + X2T_OFF + (size_t)(b*NPIX + go)*16);
    float4 v0 = x2p[0], v1 = x2p[1], v2 = x2p[2], v3 = x2p[3];
    float x2v[16] = {v0.x,v0.y,v0.z,v0.w, v1.x,v1.y,v1.z,v1.w,
                     v2.x,v2.y,v2.z,v2.w, v3.x,v3.y,v3.z,v3.w};
    float h1[16], t[16];
    #pragma unroll
    for (int c=0;c<16;c++){
      float d = x1p[c] - x2v[c];
      h1[c] = fmaxf(d*bnc[c] + bnc[16+c], 0.f);
    }
    #pragma unroll
    for (int o=0;o<16;o++){
      float a = 0.f;
      #pragma unroll
      for (int c=0;c<16;c++) a += cw1[o*16+c]*h1[c];
      t[o] = fmaxf(a*bnc[32+o] + bnc[48+o], 0.f);
    }
    if (k < 49){
      #pragma unroll
      for (int g=0;g<32;g++){
        float a = cw2b[g];
        #pragma unroll
        for (int o=0;o<16;o++) a += cw2[g*16+o]*t[o];
        wp[k*WST + g] = a;
      }
    }
  }

  // ---- phase 2: softmax over 49 taps, half-wave split (lane = half*32+g) ----
  {
    int half = lane >> 5, g = lane & 31;
    float M = -3.0e38f;
    #pragma unroll
    for (int i=0;i<25;i++){
      if (half == 0 || i < 24){
        int k = half*25 + i;
        M = fmaxf(M, wp[k*WST + g]);
      }
    }
    M = fmaxf(M, __shfl_xor(M, 32, 64));
    float s = 0.f;
    #pragma unroll
    for (int i=0;i<25;i++){
      if (half == 0 || i < 24){
        int k = half*25 + i;
        float e = __expf(wp[k*WST + g] - M);
        wp[k*WST + g] = e;
        s += e;
      }
    }
    s += __shfl_xor(s, 32, 64);
    if (half == 0) invs[wv*32 + g] = 1.f / s;
  }

  // ---- phase 3: aggregation (lane owns channels 4L..4L+3, single g) ----
  {
    int g_ = lane >> 1;
    int c0 = lane * 4;
    float inv = invs[wv*32 + g_];
    float a0=0.f,a1=0.f,a2=0.f,a3=0.f;
    const ushort_t* xb = x3b + (size_t)b*NPIX*256 + c0;
    #pragma unroll
    for (int kt=0;kt<49;kt++){
      int ii = kt/7, jj = kt - ii*7;
      int gy = refl(y + ii - 3), gx = refl(x + jj - 3);
      int gp = gy*HW + gx;                          // wave-uniform
      float wgt = wp[kt*WST + g_];
      uint2 d = *(const uint2*)(xb + (size_t)gp*256);
      a0 += wgt * blo(d.x);
      a1 += wgt * bhi(d.x);
      a2 += wgt * blo(d.y);
      a3 += wgt * bhi(d.y);
    }
    *(float4*)&ags[wv*256 + c0] = make_float4(a0*inv, a1*inv, a2*inv, a3*inv);
  }
  __syncthreads();

  // ---- phase 4: position2, block-wide (thread = out channel c, 4 px) ----
  {
    int c = tid, g4 = c >> 3;
    const float* P2 = ws + P2T_OFF;
    float i0 = invs[0*32+g4], i1 = invs[1*32+g4], i2 = invs[2*32+g4], i3 = invs[3*32+g4];
    float r0=0.f, r1=0.f, r2=0.f, r3=0.f;
    #pragma unroll
    for (int i=0;i<8;i++){
      float pv = P2[i*256 + c];
      r0 += ags[0*256 + i*32 + g4] * pv;
      r1 += ags[1*256 + i*32 + g4] * pv;
      r2 += ags[2*256 + i*32 + g4] * pv;
      r3 += ags[3*256 + i*32 + g4] * pv;
    }
    #pragma unroll 7
    for (int kt=0;kt<49;kt++){
      float pv = P2[(8+kt)*256 + c];
      r0 += w_s[0*49*WST + kt*WST + g4] * i0 * pv;
      r1 += w_s[1*49*WST + kt*WST + g4] * i1 * pv;
      r2 += w_s[2*49*WST + kt*WST + g4] * i2 * pv;
      r3 += w_s[3*49*WST + kt*WST + g4] * i3 * pv;
    }
    int pix0 = y*HW + xs4*4;
    *(float4*)(out + ((size_t)(b*256 + c))*NPIX + pix0) = make_float4(r0,r1,r2,r3);
  }
}

// ===================== launch =====================
extern "C" void kernel_launch(void* const* d_in, const int* in_sizes, int n_in,
                              void* d_out, int out_size, void* d_ws, size_t ws_size,
                              hipStream_t stream) {
  const float* x    = (const float*)d_in[0];
  const float* w1   = (const float*)d_in[1];
  const float* b1   = (const float*)d_in[2];
  const float* w2   = (const float*)d_in[3];
  const float* b2   = (const float*)d_in[4];
  const float* w3   = (const float*)d_in[5];
  const float* b3   = (const float*)d_in[6];
  const float* g1   = (const float*)d_in[7];
  const float* be1  = (const float*)d_in[8];
  const float* m1   = (const float*)d_in[9];
  const float* v1   = (const float*)d_in[10];
  const float* cw1  = (const float*)d_in[11];
  const float* g2   = (const float*)d_in[12];
  const float* be2  = (const float*)d_in[13];
  const float* m2   = (const float*)d_in[14];
  const float* v2   = (const float*)d_in[15];
  const float* cw2  = (const float*)d_in[16];
  const float* cw2b = (const float*)d_in[17];
  const float* p2   = (const float*)d_in[18];

  float* wsf = (float*)d_ws;
  ushort_t* x3b = (ushort_t*)((char*)d_ws + X3_BYTE_OFF);
  float* o = (float*)d_out;

  k0_prep<<<350, 256, 0, stream>>>(w1,b1,w2,b2,w3,b3,g1,be1,m1,v1,cw1,g2,be2,m2,v2,cw2,cw2b,p2,wsf);
  k1_proj<<<392, 256, 0, stream>>>(x, wsf, x3b);
  k2_fused<<<3136, 256, 0, stream>>>(wsf, x3b, o);
}

// Round 9
// 73.359 us; speedup vs baseline: 3.4458x; 3.4458x over previous
//
#include <hip/hip_runtime.h>

#define HW 56
#define NPIX 3136          // 56*56
#define CIN 256
#define OUTC 256

typedef unsigned short ushort_t;
typedef unsigned int uint_t;
typedef __attribute__((ext_vector_type(8))) short bf16x8;
typedef __attribute__((ext_vector_type(4))) float f32x4;

__device__ __forceinline__ float b2f(ushort_t u){ return __uint_as_float(((uint_t)u)<<16); }
__device__ __forceinline__ float blo(uint_t u){ return __uint_as_float(u<<16); }
__device__ __forceinline__ float bhi(uint_t u){ return __uint_as_float(u & 0xffff0000u); }
__device__ __forceinline__ ushort_t f2b(float f){
  uint_t u = __float_as_uint(f);
  u += 0x7fffu + ((u>>16)&1u);
  return (ushort_t)(u>>16);
}
__device__ __forceinline__ int refl(int v){ v = v<0 ? -v : v; return v>=HW ? 2*HW-2-v : v; }

// ---- workspace layout (float element offsets unless noted) ----
// B_pk (bf16 MFMA-fragment-packed proj weights): ushort[81920] = bytes [0,163840) = float [0,40960)
#define BF_OFF   40960      // bias[288] (pad 320)
#define CW1_OFF  41280      // cw1[16][16]
#define CW2_OFF  41536      // cw2[32][16]
#define CW2B_OFF 42048      // cw2b[32] (pad 64)
#define BNC_OFF  42112      // bn1s[16] bn1b[16] bn2s[16] bn2b[16]
#define P2T_OFF  42176      // P2t[57][256] = 14592
#define X1T_OFF  56768      // x1t[4][3136][16] fp32 (pixel-major)
#define X2T_OFF  257472     // x2t[4][3136][16] fp32 (pixel-major)
#define X3_BYTE_OFF 1832704 // x3b[4][3136][256] bf16 -> end 8,255,232 B (< proven 8.39 MB)

// ===================== K0: weight prep =====================
// B_pk element e = ((kt*20+nf)*64 + lane)*8 + j  holds bf16(W[n][k]),
// k = kt*32 + (lane>>4)*8 + j, n = nf*16 + (lane&15); n>=288 -> 0 (N padded to 320).
__global__ void k0_prep(const float* __restrict__ w1, const float* __restrict__ b1,
                        const float* __restrict__ w2, const float* __restrict__ b2,
                        const float* __restrict__ w3, const float* __restrict__ b3,
                        const float* __restrict__ g1, const float* __restrict__ be1,
                        const float* __restrict__ m1, const float* __restrict__ v1,
                        const float* __restrict__ cw1,
                        const float* __restrict__ g2, const float* __restrict__ be2,
                        const float* __restrict__ m2, const float* __restrict__ v2,
                        const float* __restrict__ cw2, const float* __restrict__ cw2b,
                        const float* __restrict__ p2,
                        float* __restrict__ ws)
{
  int idx = blockIdx.x*256 + threadIdx.x;
  if (idx < 81920){
    int j = idx & 7, l = (idx>>3)&63, t2 = idx>>9;   // t2 = kt*20+nf in [0,160)
    int nf = t2 % 20, kt = t2 / 20;
    int k = kt*32 + (l>>4)*8 + j;
    int n = nf*16 + (l&15);
    float v = 0.f;
    if (n < 16)       v = w1[n*256 + k];
    else if (n < 32)  v = w2[(n-16)*256 + k];
    else if (n < 288) v = w3[(n-32)*256 + k];
    ((ushort_t*)ws)[idx] = f2b(v);
    return;
  }
  int j = idx - 81920;
  if (j < 288){ ws[BF_OFF+j] = (j<16 ? b1[j] : (j<32 ? b2[j-16] : b3[j-32])); return; }
  j -= 288;
  if (j < 32){ ws[BF_OFF+288+j] = 0.f; return; }     // bias pad n=288..319
  j -= 32;
  if (j < 256){ ws[CW1_OFF+j] = cw1[j]; return; }
  j -= 256;
  if (j < 512){ ws[CW2_OFF+j] = cw2[j]; return; }
  j -= 512;
  if (j < 32){ ws[CW2B_OFF+j] = cw2b[j]; return; }
  j -= 32;
  if (j < 64){
    int set = j >> 4, c = j & 15;
    float o;
    if (set == 0){ o = g1[c] * rsqrtf(v1[c] + 1e-5f); }
    else if (set == 1){ float s = g1[c] * rsqrtf(v1[c] + 1e-5f); o = be1[c] - m1[c]*s; }
    else if (set == 2){ o = g2[c] * rsqrtf(v2[c] + 1e-5f); }
    else { float s = g2[c] * rsqrtf(v2[c] + 1e-5f); o = be2[c] - m2[c]*s; }
    ws[BNC_OFF+j] = o;
    return;
  }
  j -= 64;
  if (j < 14592){                          // P2t[i][g*8+o] = p2[(g*8+o)*57 + i]
    int i = j >> 8, rem = j & 255;
    ws[P2T_OFF + j] = p2[rem*57 + i];
    return;
  }
}

// ===================== K1 v4: MFMA projection GEMM =====================
// 196 blocks (64 px each) x 4 waves; waves split N: wave wv covers n [wv*80, wv*80+80).
// x staged once to LDS [c][px] fp32 (64 KB, proven v3 global_load_lds pattern).
// A = x^T hi/lo bf16 split (2 MFMA/tile); B = pre-packed bf16 fragments (1 dwordx4/frag).
__global__ __launch_bounds__(256,2) void k1_proj(const float* __restrict__ x,
                                                 float* __restrict__ ws,
                                                 ushort_t* __restrict__ x3b)
{
  __shared__ float xs[CIN*64];        // [c][px] fp32, 64 KB
  int t = threadIdx.x;
  int bid = blockIdx.x;               // 0..195
  int b = bid / 49, pp = (bid - b*49)*64;
  int wv = __builtin_amdgcn_readfirstlane(t >> 6);
  int lane = t & 63;

  { // ---- stage (v3-verified): lds float idx i*1024 + wv*256 + lane*4 == c*64 + px ----
    const float* src = x + (size_t)b*CIN*NPIX + pp;
    int c0 = t >> 4;
    int po = (t & 15) * 4;
    #pragma unroll
    for (int i=0;i<16;i++){
      const float* gp = src + (size_t)(i*16 + c0)*NPIX + po;
      __builtin_amdgcn_global_load_lds(
          (const __attribute__((address_space(1))) void*)gp,
          (__attribute__((address_space(3))) void*)(xs + i*1024 + wv*256),
          16, 0, 0);
    }
  }
  __syncthreads();

  // ---- accumulators init with bias (col = wv*80 + nf*16 + (lane&15), same for all 4 rows) ----
  f32x4 acc[4][5];
  float bias[5];
  #pragma unroll
  for (int nf=0;nf<5;nf++) bias[nf] = ws[BF_OFF + wv*80 + nf*16 + (lane&15)];  // pad reads 0
  #pragma unroll
  for (int m=0;m<4;m++)
    #pragma unroll
    for (int nf=0;nf<5;nf++)
      acc[m][nf] = (f32x4){bias[nf],bias[nf],bias[nf],bias[nf]};

  const uint4* bpk = (const uint4*)ws;   // fragment e16 = (kt*20+nfg)*64 + lane
  // ---- K loop: 8 tiles of 32 ----
  #pragma unroll 1
  for (int kt=0;kt<8;kt++){
    // A fragments: row = lane&15 (+m*16), k = kt*32 + (lane>>4)*8 + j
    int abase = (kt*32 + ((lane>>4)<<3))*64 + (lane&15);
    union { uint_t u[4]; bf16x8 v; } ahi[4], alo[4];
    #pragma unroll
    for (int m=0;m<4;m++){
      float f[8];
      #pragma unroll
      for (int j=0;j<8;j++) f[j] = xs[abase + j*64 + m*16];
      #pragma unroll
      for (int p=0;p<4;p++){
        uint_t u0 = __float_as_uint(f[2*p]), u1 = __float_as_uint(f[2*p+1]);
        uint_t h1 = u1 & 0xffff0000u;
        ahi[m].u[p] = (u0>>16) | h1;
        float l0 = f[2*p]   - __uint_as_float(u0 & 0xffff0000u);
        float l1 = f[2*p+1] - __uint_as_float(h1);
        alo[m].u[p] = (__float_as_uint(l0)>>16) | (__float_as_uint(l1) & 0xffff0000u);
      }
    }
    // B fragments (L2-hot, coalesced) + MFMA
    #pragma unroll
    for (int nf=0;nf<5;nf++){
      union { uint4 q; bf16x8 v; } bw;
      bw.q = bpk[(size_t)(kt*20 + wv*5 + nf)*64 + lane];
      #pragma unroll
      for (int m=0;m<4;m++){
        acc[m][nf] = __builtin_amdgcn_mfma_f32_16x16x32_bf16(ahi[m].v, bw.v, acc[m][nf], 0,0,0);
        acc[m][nf] = __builtin_amdgcn_mfma_f32_16x16x32_bf16(alo[m].v, bw.v, acc[m][nf], 0,0,0);
      }
    }
  }

  // ---- epilogue: D row = m*16 + (lane>>4)*4 + r, col = wv*80 + nf*16 + (lane&15) ----
  #pragma unroll
  for (int m=0;m<4;m++){
    #pragma unroll
    for (int r=0;r<4;r++){
      int sp = pp + m*16 + ((lane>>4)<<2) + r;
      #pragma unroll
      for (int nf=0;nf<5;nf++){
        int n = wv*80 + nf*16 + (lane&15);
        float val = acc[m][nf][r];
        if (n < 16){
          ws[X1T_OFF + (size_t)(b*NPIX + sp)*16 + n] = val;
        } else if (n < 32){
          ws[X2T_OFF + (size_t)(b*NPIX + sp)*16 + (n-16)] = val;
        } else if (n < 288){
          x3b[((size_t)b*NPIX + sp)*256 + (n-32)] = f2b(val);
        }
      }
    }
  }
}

// ===================== K2: fused attention, wave-per-pixel (unchanged) =====================
#define WST 33              // w_s row stride (floats)
__global__ __launch_bounds__(256,5) void k2_fused(const float* __restrict__ ws,
                                                  const ushort_t* __restrict__ x3b,
                                                  float* __restrict__ out)
{
  __shared__ float w_s[4*49*WST + 4];   // per-wave [49][32] (stride 33), unnormalized exp
  __shared__ __align__(16) float ags[4*256];
  __shared__ float invs[4*32];

  int tid = threadIdx.x;
  int bid0 = blockIdx.x;
  int bid = (bid0 & 7)*392 + (bid0 >> 3);     // XCD-contiguous pixel spans
  int b = bid / 784; int rem = bid - b*784;
  int row = rem / 14, xs4 = rem - row*14;
  int wv = __builtin_amdgcn_readfirstlane(tid >> 6);
  int lane = tid & 63;
  int y = row, x = xs4*4 + wv;
  int pix = y*HW + x;

  const float* bnc  = ws + BNC_OFF;
  const float* cw1  = ws + CW1_OFF;
  const float* cw2  = ws + CW2_OFF;
  const float* cw2b = ws + CW2B_OFF;
  float* wp = w_s + wv*49*WST;

  // ---- phase 1: per-tap MLP (lane = tap) ----
  {
    int k = lane;
    int kk = k < 49 ? k : 48;
    int ki = kk / 7, kj = kk - ki*7;
    int gy = refl(y + ki - 3), gx = refl(x + kj - 3);
    int go = gy*HW + gx;

    const float*  x1p = ws + X1T_OFF + (size_t)(b*NPIX + pix)*16;   // uniform -> s_load
    const float4* x2p = (const float4*)(ws + X2T_OFF + (size_t)(b*NPIX + go)*16);
    float4 v0 = x2p[0], v1 = x2p[1], v2 = x2p[2], v3 = x2p[3];
    float x2v[16] = {v0.x,v0.y,v0.z,v0.w, v1.x,v1.y,v1.z,v1.w,
                     v2.x,v2.y,v2.z,v2.w, v3.x,v3.y,v3.z,v3.w};
    float h1[16], tt[16];
    #pragma unroll
    for (int c=0;c<16;c++){
      float d = x1p[c] - x2v[c];
      h1[c] = fmaxf(d*bnc[c] + bnc[16+c], 0.f);
    }
    #pragma unroll
    for (int o=0;o<16;o++){
      float a = 0.f;
      #pragma unroll
      for (int c=0;c<16;c++) a += cw1[o*16+c]*h1[c];
      tt[o] = fmaxf(a*bnc[32+o] + bnc[48+o], 0.f);
    }
    if (k < 49){
      #pragma unroll
      for (int g=0;g<32;g++){
        float a = cw2b[g];
        #pragma unroll
        for (int o=0;o<16;o++) a += cw2[g*16+o]*tt[o];
        wp[k*WST + g] = a;
      }
    }
  }

  // ---- phase 2: softmax over 49 taps, half-wave split (lane = half*32+g) ----
  {
    int half = lane >> 5, g = lane & 31;
    float M = -3.0e38f;
    #pragma unroll
    for (int i=0;i<25;i++){
      if (half == 0 || i < 24){
        int k = half*25 + i;
        M = fmaxf(M, wp[k*WST + g]);
      }
    }
    M = fmaxf(M, __shfl_xor(M, 32, 64));
    float s = 0.f;
    #pragma unroll
    for (int i=0;i<25;i++){
      if (half == 0 || i < 24){
        int k = half*25 + i;
        float e = __expf(wp[k*WST + g] - M);
        wp[k*WST + g] = e;
        s += e;
      }
    }
    s += __shfl_xor(s, 32, 64);
    if (half == 0) invs[wv*32 + g] = 1.f / s;
  }

  // ---- phase 3: aggregation (lane owns channels 4L..4L+3, single g) ----
  {
    int g_ = lane >> 1;
    int c0 = lane * 4;
    float inv = invs[wv*32 + g_];
    float a0=0.f,a1=0.f,a2=0.f,a3=0.f;
    const ushort_t* xb = x3b + (size_t)b*NPIX*256 + c0;
    #pragma unroll
    for (int kt=0;kt<49;kt++){
      int ii = kt/7, jj = kt - ii*7;
      int gy = refl(y + ii - 3), gx = refl(x + jj - 3);
      int gp = gy*HW + gx;                          // wave-uniform
      float wgt = wp[kt*WST + g_];
      uint2 d = *(const uint2*)(xb + (size_t)gp*256);
      a0 += wgt * blo(d.x);
      a1 += wgt * bhi(d.x);
      a2 += wgt * blo(d.y);
      a3 += wgt * bhi(d.y);
    }
    *(float4*)&ags[wv*256 + c0] = make_float4(a0*inv, a1*inv, a2*inv, a3*inv);
  }
  __syncthreads();

  // ---- phase 4: position2, block-wide (thread = out channel c, 4 px) ----
  {
    int c = tid, g4 = c >> 3;
    const float* P2 = ws + P2T_OFF;
    float i0 = invs[0*32+g4], i1 = invs[1*32+g4], i2 = invs[2*32+g4], i3 = invs[3*32+g4];
    float r0=0.f, r1=0.f, r2=0.f, r3=0.f;
    #pragma unroll
    for (int i=0;i<8;i++){
      float pv = P2[i*256 + c];
      r0 += ags[0*256 + i*32 + g4] * pv;
      r1 += ags[1*256 + i*32 + g4] * pv;
      r2 += ags[2*256 + i*32 + g4] * pv;
      r3 += ags[3*256 + i*32 + g4] * pv;
    }
    #pragma unroll 7
    for (int kt=0;kt<49;kt++){
      float pv = P2[(8+kt)*256 + c];
      r0 += w_s[0*49*WST + kt*WST + g4] * i0 * pv;
      r1 += w_s[1*49*WST + kt*WST + g4] * i1 * pv;
      r2 += w_s[2*49*WST + kt*WST + g4] * i2 * pv;
      r3 += w_s[3*49*WST + kt*WST + g4] * i3 * pv;
    }
    int pix0 = y*HW + xs4*4;
    *(float4*)(out + ((size_t)(b*256 + c))*NPIX + pix0) = make_float4(r0,r1,r2,r3);
  }
}

// ===================== launch =====================
extern "C" void kernel_launch(void* const* d_in, const int* in_sizes, int n_in,
                              void* d_out, int out_size, void* d_ws, size_t ws_size,
                              hipStream_t stream) {
  const float* x    = (const float*)d_in[0];
  const float* w1   = (const float*)d_in[1];
  const float* b1   = (const float*)d_in[2];
  const float* w2   = (const float*)d_in[3];
  const float* b2   = (const float*)d_in[4];
  const float* w3   = (const float*)d_in[5];
  const float* b3   = (const float*)d_in[6];
  const float* g1   = (const float*)d_in[7];
  const float* be1  = (const float*)d_in[8];
  const float* m1   = (const float*)d_in[9];
  const float* v1   = (const float*)d_in[10];
  const float* cw1  = (const float*)d_in[11];
  const float* g2   = (const float*)d_in[12];
  const float* be2  = (const float*)d_in[13];
  const float* m2   = (const float*)d_in[14];
  const float* v2   = (const float*)d_in[15];
  const float* cw2  = (const float*)d_in[16];
  const float* cw2b = (const float*)d_in[17];
  const float* p2   = (const float*)d_in[18];

  float* wsf = (float*)d_ws;
  ushort_t* x3b = (ushort_t*)((char*)d_ws + X3_BYTE_OFF);
  float* o = (float*)d_out;

  k0_prep<<<382, 256, 0, stream>>>(w1,b1,w2,b2,w3,b3,g1,be1,m1,v1,cw1,g2,be2,m2,v2,cw2,cw2b,p2,wsf);
  k1_proj<<<196, 256, 0, stream>>>(x, wsf, x3b);
  k2_fused<<<3136, 256, 0, stream>>>(wsf, x3b, o);
}

// Round 12
// 67.260 us; speedup vs baseline: 3.7582x; 1.0907x over previous
//
#include <hip/hip_runtime.h>

#define HW 56
#define NPIX 3136          // 56*56
#define CIN 256
#define OUTC 256

typedef unsigned short ushort_t;
typedef unsigned int uint_t;
typedef __attribute__((ext_vector_type(8))) short bf16x8;
typedef __attribute__((ext_vector_type(4))) float f32x4;
typedef __attribute__((ext_vector_type(2))) __fp16 half2v;   // cvt_pkrtz/fdot2 native type

__device__ __forceinline__ ushort_t f2b(float f){
  uint_t u = __float_as_uint(f);
  u += 0x7fffu + ((u>>16)&1u);
  return (ushort_t)(u>>16);
}
__device__ __forceinline__ int refl(int v){ v = v<0 ? -v : v; return v>=HW ? 2*HW-2-v : v; }

// ---- workspace layout (float element offsets unless noted) ----
// B_pk (bf16 MFMA-fragment-packed proj weights): ushort[81920] = float [0,40960)
#define BF_OFF   40960      // bias[288] (pad 320)
#define CW1H_OFF 41280      // cw1 half2-packed: uint[128] = [o<16][p<8]
#define CW2H_OFF 41536      // cw2 half2-packed: uint[256] = [g<32][p<8]
#define CW2B_OFF 42048      // cw2b[32] (pad 64)
#define BNC_OFF  42112      // bn1s[16] bn1b[16] bn2s[16] bn2b[16]
#define P2T_OFF  42176      // P2t[57][256] = 14592
#define X1T_OFF  56768      // x1t[4][3136][16] fp32 (pixel-major)
#define X2T_OFF  257472     // x2t[4][3136][16] fp32 (pixel-major)
#define X3_BYTE_OFF 1832704 // x3h[4][3136][256] fp16 -> end 8,255,232 B (< proven 8.39 MB)

// ===================== K0: weight prep =====================
__global__ void k0_prep(const float* __restrict__ w1, const float* __restrict__ b1,
                        const float* __restrict__ w2, const float* __restrict__ b2,
                        const float* __restrict__ w3, const float* __restrict__ b3,
                        const float* __restrict__ g1, const float* __restrict__ be1,
                        const float* __restrict__ m1, const float* __restrict__ v1,
                        const float* __restrict__ cw1,
                        const float* __restrict__ g2, const float* __restrict__ be2,
                        const float* __restrict__ m2, const float* __restrict__ v2,
                        const float* __restrict__ cw2, const float* __restrict__ cw2b,
                        const float* __restrict__ p2,
                        float* __restrict__ ws)
{
  int idx = blockIdx.x*256 + threadIdx.x;
  if (idx < 81920){   // B_pk: k = kt*32+(l>>4)*8+j, n = nf*16+(l&15); n>=288 -> 0
    int j = idx & 7, l = (idx>>3)&63, t2 = idx>>9;
    int nf = t2 % 20, kt = t2 / 20;
    int k = kt*32 + (l>>4)*8 + j;
    int n = nf*16 + (l&15);
    float v = 0.f;
    if (n < 16)       v = w1[n*256 + k];
    else if (n < 32)  v = w2[(n-16)*256 + k];
    else if (n < 288) v = w3[(n-32)*256 + k];
    ((ushort_t*)ws)[idx] = f2b(v);
    return;
  }
  int j = idx - 81920;
  if (j < 288){ ws[BF_OFF+j] = (j<16 ? b1[j] : (j<32 ? b2[j-16] : b3[j-32])); return; }
  j -= 288;
  if (j < 32){ ws[BF_OFF+288+j] = 0.f; return; }
  j -= 32;
  if (j < 128){                          // cw1h[o][p] = half2(cw1[o][2p], cw1[o][2p+1])
    int o = j>>3, p = j&7;
    union { __fp16 h[2]; uint_t u; } cv;
    cv.h[0] = (__fp16)cw1[o*16 + 2*p];
    cv.h[1] = (__fp16)cw1[o*16 + 2*p+1];
    ((uint_t*)ws)[CW1H_OFF + j] = cv.u;
    return;
  }
  j -= 128;
  if (j < 256){                          // cw2h[g][p]
    int g = j>>3, p = j&7;
    union { __fp16 h[2]; uint_t u; } cv;
    cv.h[0] = (__fp16)cw2[g*16 + 2*p];
    cv.h[1] = (__fp16)cw2[g*16 + 2*p+1];
    ((uint_t*)ws)[CW2H_OFF + j] = cv.u;
    return;
  }
  j -= 256;
  if (j < 32){ ws[CW2B_OFF+j] = cw2b[j]; return; }
  j -= 32;
  if (j < 64){
    int set = j >> 4, c = j & 15;
    float o;
    if (set == 0){ o = g1[c] * rsqrtf(v1[c] + 1e-5f); }
    else if (set == 1){ float s = g1[c] * rsqrtf(v1[c] + 1e-5f); o = be1[c] - m1[c]*s; }
    else if (set == 2){ o = g2[c] * rsqrtf(v2[c] + 1e-5f); }
    else { float s = g2[c] * rsqrtf(v2[c] + 1e-5f); o = be2[c] - m2[c]*s; }
    ws[BNC_OFF+j] = o;
    return;
  }
  j -= 64;
  if (j < 14592){                        // P2t[i][g*8+o] = p2[(g*8+o)*57 + i]
    int i = j >> 8, rem = j & 255;
    ws[P2T_OFF + j] = p2[rem*57 + i];
    return;
  }
}

// ===================== K1 v4: MFMA projection GEMM =====================
__global__ __launch_bounds__(256,2) void k1_proj(const float* __restrict__ x,
                                                 float* __restrict__ ws,
                                                 _Float16* __restrict__ x3h)
{
  __shared__ float xs[CIN*64];        // [c][px] fp32, 64 KB
  int t = threadIdx.x;
  int bid = blockIdx.x;               // 0..195
  int b = bid / 49, pp = (bid - b*49)*64;
  int wv = __builtin_amdgcn_readfirstlane(t >> 6);
  int lane = t & 63;

  { // ---- stage (v3-verified): lds float idx i*1024 + wv*256 + lane*4 == c*64 + px ----
    const float* src = x + (size_t)b*CIN*NPIX + pp;
    int c0 = t >> 4;
    int po = (t & 15) * 4;
    #pragma unroll
    for (int i=0;i<16;i++){
      const float* gp = src + (size_t)(i*16 + c0)*NPIX + po;
      __builtin_amdgcn_global_load_lds(
          (const __attribute__((address_space(1))) void*)gp,
          (__attribute__((address_space(3))) void*)(xs + i*1024 + wv*256),
          16, 0, 0);
    }
  }
  __syncthreads();

  f32x4 acc[4][5];
  float bias[5];
  #pragma unroll
  for (int nf=0;nf<5;nf++) bias[nf] = ws[BF_OFF + wv*80 + nf*16 + (lane&15)];
  #pragma unroll
  for (int m=0;m<4;m++)
    #pragma unroll
    for (int nf=0;nf<5;nf++)
      acc[m][nf] = (f32x4){bias[nf],bias[nf],bias[nf],bias[nf]};

  const uint4* bpk = (const uint4*)ws;
  #pragma unroll 1
  for (int kt=0;kt<8;kt++){
    int abase = (kt*32 + ((lane>>4)<<3))*64 + (lane&15);
    union { uint_t u[4]; bf16x8 v; } ahi[4], alo[4];
    #pragma unroll
    for (int m=0;m<4;m++){
      float f[8];
      #pragma unroll
      for (int j=0;j<8;j++) f[j] = xs[abase + j*64 + m*16];
      #pragma unroll
      for (int p=0;p<4;p++){
        uint_t u0 = __float_as_uint(f[2*p]), u1 = __float_as_uint(f[2*p+1]);
        uint_t h1 = u1 & 0xffff0000u;
        ahi[m].u[p] = (u0>>16) | h1;
        float l0 = f[2*p]   - __uint_as_float(u0 & 0xffff0000u);
        float l1 = f[2*p+1] - __uint_as_float(h1);
        alo[m].u[p] = (__float_as_uint(l0)>>16) | (__float_as_uint(l1) & 0xffff0000u);
      }
    }
    #pragma unroll
    for (int nf=0;nf<5;nf++){
      union { uint4 q; bf16x8 v; } bw;
      bw.q = bpk[(size_t)(kt*20 + wv*5 + nf)*64 + lane];
      #pragma unroll
      for (int m=0;m<4;m++){
        acc[m][nf] = __builtin_amdgcn_mfma_f32_16x16x32_bf16(ahi[m].v, bw.v, acc[m][nf], 0,0,0);
        acc[m][nf] = __builtin_amdgcn_mfma_f32_16x16x32_bf16(alo[m].v, bw.v, acc[m][nf], 0,0,0);
      }
    }
  }

  #pragma unroll
  for (int m=0;m<4;m++){
    #pragma unroll
    for (int r=0;r<4;r++){
      int sp = pp + m*16 + ((lane>>4)<<2) + r;
      #pragma unroll
      for (int nf=0;nf<5;nf++){
        int n = wv*80 + nf*16 + (lane&15);
        float val = acc[m][nf][r];
        if (n < 16){
          ws[X1T_OFF + (size_t)(b*NPIX + sp)*16 + n] = val;
        } else if (n < 32){
          ws[X2T_OFF + (size_t)(b*NPIX + sp)*16 + (n-16)] = val;
        } else if (n < 288){
          x3h[((size_t)b*NPIX + sp)*256 + (n-32)] = (_Float16)val;
        }
      }
    }
  }
}

// ===================== K2: fused attention, wave-per-pixel =====================
#define WST 33              // w_s row stride (floats)
__global__ __launch_bounds__(256,5) void k2_fused(const float* __restrict__ ws,
                                                  const _Float16* __restrict__ x3h,
                                                  float* __restrict__ out)
{
  __shared__ float w_s[4*49*WST + 4];   // per-wave [49][32] (stride 33), NORMALIZED w
  __shared__ __align__(16) float ags[4*256];

  int tid = threadIdx.x;
  int bid0 = blockIdx.x;
  int bid = (bid0 & 7)*392 + (bid0 >> 3);     // XCD-contiguous pixel spans
  int b = bid / 784; int rem = bid - b*784;
  int row = rem / 14, xs4 = rem - row*14;
  int wv = __builtin_amdgcn_readfirstlane(tid >> 6);
  int lane = tid & 63;
  int y = row, x = xs4*4 + wv;
  int pix = y*HW + x;

  const float* bnc  = ws + BNC_OFF;
  const uint_t* c1h = (const uint_t*)ws + CW1H_OFF;
  const uint_t* c2h = (const uint_t*)ws + CW2H_OFF;
  const float* cw2b = ws + CW2B_OFF;
  float* wp = w_s + wv*49*WST;

  // ---- phase 1: per-tap MLP (lane = tap), GEMMs via f16 dot2 ----
  {
    int k = lane;
    int kk = k < 49 ? k : 48;
    int ki = kk / 7, kj = kk - ki*7;
    int gy = refl(y + ki - 3), gx = refl(x + kj - 3);
    int go = gy*HW + gx;

    const float*  x1p = ws + X1T_OFF + (size_t)(b*NPIX + pix)*16;   // uniform -> s_load
    const float4* x2p = (const float4*)(ws + X2T_OFF + (size_t)(b*NPIX + go)*16);
    float4 v0 = x2p[0], v1 = x2p[1], v2 = x2p[2], v3 = x2p[3];
    float x2v[16] = {v0.x,v0.y,v0.z,v0.w, v1.x,v1.y,v1.z,v1.w,
                     v2.x,v2.y,v2.z,v2.w, v3.x,v3.y,v3.z,v3.w};
    float h1[16];
    #pragma unroll
    for (int c=0;c<16;c++){
      float d = x1p[c] - x2v[c];
      h1[c] = fmaxf(d*bnc[c] + bnc[16+c], 0.f);
    }
    half2v hp[8];
    #pragma unroll
    for (int p=0;p<8;p++) hp[p] = __builtin_amdgcn_cvt_pkrtz(h1[2*p], h1[2*p+1]);

    float tt[16];
    #pragma unroll
    for (int o=0;o<16;o++){
      float a = 0.f;
      #pragma unroll
      for (int p=0;p<8;p++){
        union { uint_t u; half2v h; } cv; cv.u = c1h[o*8+p];
        a = __builtin_amdgcn_fdot2(hp[p], cv.h, a, false);
      }
      tt[o] = fmaxf(a*bnc[32+o] + bnc[48+o], 0.f);
    }
    half2v tp[8];
    #pragma unroll
    for (int p=0;p<8;p++) tp[p] = __builtin_amdgcn_cvt_pkrtz(tt[2*p], tt[2*p+1]);

    if (k < 49){
      #pragma unroll
      for (int g=0;g<32;g++){
        float a = cw2b[g];
        #pragma unroll
        for (int p=0;p<8;p++){
          union { uint_t u; half2v h; } cv; cv.u = c2h[g*8+p];
          a = __builtin_amdgcn_fdot2(tp[p], cv.h, a, false);
        }
        wp[k*WST + g] = a;
      }
    }
  }

  // ---- phase 2: softmax over 49 taps, half-wave split; store NORMALIZED w ----
  {
    int half = lane >> 5, g = lane & 31;
    float e[25];
    float M = -3.0e38f;
    #pragma unroll
    for (int i=0;i<25;i++){
      if (half == 0 || i < 24){
        e[i] = wp[(half*25 + i)*WST + g];
        M = fmaxf(M, e[i]);
      }
    }
    M = fmaxf(M, __shfl_xor(M, 32, 64));
    float s = 0.f;
    #pragma unroll
    for (int i=0;i<25;i++){
      if (half == 0 || i < 24){
        e[i] = __expf(e[i] - M);
        s += e[i];
      }
    }
    s += __shfl_xor(s, 32, 64);
    float inv = 1.f / s;
    #pragma unroll
    for (int i=0;i<25;i++){
      if (half == 0 || i < 24) wp[(half*25 + i)*WST + g] = e[i] * inv;
    }
  }

  // ---- phase 3: aggregation (lane owns channels 4L..4L+3, single g) ----
  {
    int g_ = lane >> 1;
    int c0 = lane * 4;
    float a0=0.f,a1=0.f,a2=0.f,a3=0.f;
    const _Float16* xb = x3h + (size_t)b*NPIX*256 + c0;
    #pragma unroll
    for (int kt=0;kt<49;kt++){
      int ii = kt/7, jj = kt - ii*7;
      int gy = refl(y + ii - 3), gx = refl(x + jj - 3);
      int gp = gy*HW + gx;                          // wave-uniform
      float wgt = wp[kt*WST + g_];
      union { uint2 u; _Float16 h[4]; } d;
      d.u = *(const uint2*)(xb + (size_t)gp*256);
      a0 += wgt * (float)d.h[0];
      a1 += wgt * (float)d.h[1];
      a2 += wgt * (float)d.h[2];
      a3 += wgt * (float)d.h[3];
    }
    *(float4*)&ags[wv*256 + c0] = make_float4(a0,a1,a2,a3);
  }
  __syncthreads();

  // ---- phase 4: position2, block-wide (thread = out channel c, 4 px) ----
  {
    int c = tid, g4 = c >> 3;
    const float* P2 = ws + P2T_OFF;
    float r0=0.f, r1=0.f, r2=0.f, r3=0.f;
    #pragma unroll
    for (int i=0;i<8;i++){
      float pv = P2[i*256 + c];
      r0 += ags[0*256 + i*32 + g4] * pv;
      r1 += ags[1*256 + i*32 + g4] * pv;
      r2 += ags[2*256 + i*32 + g4] * pv;
      r3 += ags[3*256 + i*32 + g4] * pv;
    }
    #pragma unroll 7
    for (int kt=0;kt<49;kt++){
      float pv = P2[(8+kt)*256 + c];
      r0 += w_s[0*49*WST + kt*WST + g4] * pv;
      r1 += w_s[1*49*WST + kt*WST + g4] * pv;
      r2 += w_s[2*49*WST + kt*WST + g4] * pv;
      r3 += w_s[3*49*WST + kt*WST + g4] * pv;
    }
    int pix0 = y*HW + xs4*4;
    *(float4*)(out + ((size_t)(b*256 + c))*NPIX + pix0) = make_float4(r0,r1,r2,r3);
  }
}

// ===================== launch =====================
extern "C" void kernel_launch(void* const* d_in, const int* in_sizes, int n_in,
                              void* d_out, int out_size, void* d_ws, size_t ws_size,
                              hipStream_t stream) {
  const float* x    = (const float*)d_in[0];
  const float* w1   = (const float*)d_in[1];
  const float* b1   = (const float*)d_in[2];
  const float* w2   = (const float*)d_in[3];
  const float* b2   = (const float*)d_in[4];
  const float* w3   = (const float*)d_in[5];
  const float* b3   = (const float*)d_in[6];
  const float* g1   = (const float*)d_in[7];
  const float* be1  = (const float*)d_in[8];
  const float* m1   = (const float*)d_in[9];
  const float* v1   = (const float*)d_in[10];
  const float* cw1  = (const float*)d_in[11];
  const float* g2   = (const float*)d_in[12];
  const float* be2  = (const float*)d_in[13];
  const float* m2   = (const float*)d_in[14];
  const float* v2   = (const float*)d_in[15];
  const float* cw2  = (const float*)d_in[16];
  const float* cw2b = (const float*)d_in[17];
  const float* p2   = (const float*)d_in[18];

  float* wsf = (float*)d_ws;
  _Float16* x3h = (_Float16*)((char*)d_ws + X3_BYTE_OFF);
  float* o = (float*)d_out;

  k0_prep<<<381, 256, 0, stream>>>(w1,b1,w2,b2,w3,b3,g1,be1,m1,v1,cw1,g2,be2,m2,v2,cw2,cw2b,p2,wsf);
  k1_proj<<<196, 256, 0, stream>>>(x, wsf, x3h);
  k2_fused<<<3136, 256, 0, stream>>>(wsf, x3h, o);
}

// Round 13
// 64.712 us; speedup vs baseline: 3.9062x; 1.0394x over previous
//
#include <hip/hip_runtime.h>

#define HW 56
#define NPIX 3136          // 56*56
#define CIN 256
#define OUTC 256

typedef unsigned short ushort_t;
typedef unsigned int uint_t;
typedef __attribute__((ext_vector_type(8))) short bf16x8;
typedef __attribute__((ext_vector_type(4))) float f32x4;
typedef __attribute__((ext_vector_type(2))) __fp16 half2v;   // cvt_pkrtz/fdot2 native type

__device__ __forceinline__ ushort_t f2b(float f){
  uint_t u = __float_as_uint(f);
  u += 0x7fffu + ((u>>16)&1u);
  return (ushort_t)(u>>16);
}
__device__ __forceinline__ int refl(int v){ v = v<0 ? -v : v; return v>=HW ? 2*HW-2-v : v; }

// ---- workspace layout (4-byte element offsets unless noted) ----
// B_pk (bf16 MFMA-fragment-packed proj weights): ushort[81920] = elem [0,40960)
#define BF_OFF   40960      // bias[288] (pad 320)
#define CW1H_OFF 41280      // cw1 half2-packed: uint[128] = [o<16][p<8]
#define CW2H_OFF 41536      // cw2 half2-packed: uint[256] = [g<32][p<8]
#define CW2B_OFF 42048      // cw2b[32] (pad 64)
#define BNC_OFF  42112      // bn1s[16] bn1b[16] bn2s[16] bn2b[16]
#define P2T_OFF  42176      // P2t[57][256] fp32 = 14592 (rows 0-7 used by i-loop)
#define P2H_OFF  56768      // P2H[25][256] uint: half2(P2[tap 2p][c], P2[tap 2p+1][c]) = 25600
#define X1T_OFF  82368      // x1t[4][3136][16] fp32 (pixel-major)
#define X2T_OFF  283072     // x2t[4][3136][16] fp32 (pixel-major)
#define X3_BYTE_OFF 1935104 // x3h[4][3136][256] fp16 -> end 8,357,632 B (< proven 8.39 MB)

// ===================== K0: weight prep =====================
__global__ void k0_prep(const float* __restrict__ w1, const float* __restrict__ b1,
                        const float* __restrict__ w2, const float* __restrict__ b2,
                        const float* __restrict__ w3, const float* __restrict__ b3,
                        const float* __restrict__ g1, const float* __restrict__ be1,
                        const float* __restrict__ m1, const float* __restrict__ v1,
                        const float* __restrict__ cw1,
                        const float* __restrict__ g2, const float* __restrict__ be2,
                        const float* __restrict__ m2, const float* __restrict__ v2,
                        const float* __restrict__ cw2, const float* __restrict__ cw2b,
                        const float* __restrict__ p2,
                        float* __restrict__ ws)
{
  int idx = blockIdx.x*256 + threadIdx.x;
  if (idx < 81920){   // B_pk: k = kt*32+(l>>4)*8+j, n = nf*16+(l&15); n>=288 -> 0
    int j = idx & 7, l = (idx>>3)&63, t2 = idx>>9;
    int nf = t2 % 20, kt = t2 / 20;
    int k = kt*32 + (l>>4)*8 + j;
    int n = nf*16 + (l&15);
    float v = 0.f;
    if (n < 16)       v = w1[n*256 + k];
    else if (n < 32)  v = w2[(n-16)*256 + k];
    else if (n < 288) v = w3[(n-32)*256 + k];
    ((ushort_t*)ws)[idx] = f2b(v);
    return;
  }
  int j = idx - 81920;
  if (j < 288){ ws[BF_OFF+j] = (j<16 ? b1[j] : (j<32 ? b2[j-16] : b3[j-32])); return; }
  j -= 288;
  if (j < 32){ ws[BF_OFF+288+j] = 0.f; return; }
  j -= 32;
  if (j < 128){                          // cw1h[o][p]
    int o = j>>3, p = j&7;
    union { __fp16 h[2]; uint_t u; } cv;
    cv.h[0] = (__fp16)cw1[o*16 + 2*p];
    cv.h[1] = (__fp16)cw1[o*16 + 2*p+1];
    ((uint_t*)ws)[CW1H_OFF + j] = cv.u;
    return;
  }
  j -= 128;
  if (j < 256){                          // cw2h[g][p]
    int g = j>>3, p = j&7;
    union { __fp16 h[2]; uint_t u; } cv;
    cv.h[0] = (__fp16)cw2[g*16 + 2*p];
    cv.h[1] = (__fp16)cw2[g*16 + 2*p+1];
    ((uint_t*)ws)[CW2H_OFF + j] = cv.u;
    return;
  }
  j -= 256;
  if (j < 32){ ws[CW2B_OFF+j] = cw2b[j]; return; }
  j -= 32;
  if (j < 64){
    int set = j >> 4, c = j & 15;
    float o;
    if (set == 0){ o = g1[c] * rsqrtf(v1[c] + 1e-5f); }
    else if (set == 1){ float s = g1[c] * rsqrtf(v1[c] + 1e-5f); o = be1[c] - m1[c]*s; }
    else if (set == 2){ o = g2[c] * rsqrtf(v2[c] + 1e-5f); }
    else { float s = g2[c] * rsqrtf(v2[c] + 1e-5f); o = be2[c] - m2[c]*s; }
    ws[BNC_OFF+j] = o;
    return;
  }
  j -= 64;
  if (j < 14592){                        // P2t[i][g*8+o] = p2[(g*8+o)*57 + i]
    int i = j >> 8, rem = j & 255;
    ws[P2T_OFF + j] = p2[rem*57 + i];
    return;
  }
  j -= 14592;
  if (j < 25600){                        // P2H[p][c] = half2(row 8+2p, row 9+2p)
    int p = j >> 8, c = j & 255;
    union { __fp16 h[2]; uint_t u; } cv;
    cv.h[0] = (__fp16)p2[c*57 + 8 + 2*p];
    cv.h[1] = (2*p+1 < 49) ? (__fp16)p2[c*57 + 9 + 2*p] : (__fp16)0.f;
    ((uint_t*)ws)[P2H_OFF + j] = cv.u;
    return;
  }
}

// ===================== K1 v4: MFMA projection GEMM =====================
__global__ __launch_bounds__(256,2) void k1_proj(const float* __restrict__ x,
                                                 float* __restrict__ ws,
                                                 _Float16* __restrict__ x3h)
{
  __shared__ float xs[CIN*64];        // [c][px] fp32, 64 KB
  int t = threadIdx.x;
  int bid = blockIdx.x;               // 0..195
  int b = bid / 49, pp = (bid - b*49)*64;
  int wv = __builtin_amdgcn_readfirstlane(t >> 6);
  int lane = t & 63;

  { // ---- stage (v3-verified): lds float idx i*1024 + wv*256 + lane*4 == c*64 + px ----
    const float* src = x + (size_t)b*CIN*NPIX + pp;
    int c0 = t >> 4;
    int po = (t & 15) * 4;
    #pragma unroll
    for (int i=0;i<16;i++){
      const float* gp = src + (size_t)(i*16 + c0)*NPIX + po;
      __builtin_amdgcn_global_load_lds(
          (const __attribute__((address_space(1))) void*)gp,
          (__attribute__((address_space(3))) void*)(xs + i*1024 + wv*256),
          16, 0, 0);
    }
  }
  __syncthreads();

  f32x4 acc[4][5];
  float bias[5];
  #pragma unroll
  for (int nf=0;nf<5;nf++) bias[nf] = ws[BF_OFF + wv*80 + nf*16 + (lane&15)];
  #pragma unroll
  for (int m=0;m<4;m++)
    #pragma unroll
    for (int nf=0;nf<5;nf++)
      acc[m][nf] = (f32x4){bias[nf],bias[nf],bias[nf],bias[nf]};

  const uint4* bpk = (const uint4*)ws;
  #pragma unroll 1
  for (int kt=0;kt<8;kt++){
    int abase = (kt*32 + ((lane>>4)<<3))*64 + (lane&15);
    union { uint_t u[4]; bf16x8 v; } ahi[4], alo[4];
    #pragma unroll
    for (int m=0;m<4;m++){
      float f[8];
      #pragma unroll
      for (int j=0;j<8;j++) f[j] = xs[abase + j*64 + m*16];
      #pragma unroll
      for (int p=0;p<4;p++){
        uint_t u0 = __float_as_uint(f[2*p]), u1 = __float_as_uint(f[2*p+1]);
        uint_t h1 = u1 & 0xffff0000u;
        ahi[m].u[p] = (u0>>16) | h1;
        float l0 = f[2*p]   - __uint_as_float(u0 & 0xffff0000u);
        float l1 = f[2*p+1] - __uint_as_float(h1);
        alo[m].u[p] = (__float_as_uint(l0)>>16) | (__float_as_uint(l1) & 0xffff0000u);
      }
    }
    #pragma unroll
    for (int nf=0;nf<5;nf++){
      union { uint4 q; bf16x8 v; } bw;
      bw.q = bpk[(size_t)(kt*20 + wv*5 + nf)*64 + lane];
      #pragma unroll
      for (int m=0;m<4;m++){
        acc[m][nf] = __builtin_amdgcn_mfma_f32_16x16x32_bf16(ahi[m].v, bw.v, acc[m][nf], 0,0,0);
        acc[m][nf] = __builtin_amdgcn_mfma_f32_16x16x32_bf16(alo[m].v, bw.v, acc[m][nf], 0,0,0);
      }
    }
  }

  #pragma unroll
  for (int m=0;m<4;m++){
    #pragma unroll
    for (int r=0;r<4;r++){
      int sp = pp + m*16 + ((lane>>4)<<2) + r;
      #pragma unroll
      for (int nf=0;nf<5;nf++){
        int n = wv*80 + nf*16 + (lane&15);
        float val = acc[m][nf][r];
        if (n < 16){
          ws[X1T_OFF + (size_t)(b*NPIX + sp)*16 + n] = val;
        } else if (n < 32){
          ws[X2T_OFF + (size_t)(b*NPIX + sp)*16 + (n-16)] = val;
        } else if (n < 288){
          x3h[((size_t)b*NPIX + sp)*256 + (n-32)] = (_Float16)val;
        }
      }
    }
  }
}

// ===================== K2: fused attention, wave-per-pixel =====================
// lgw per wave (840 u32): rows [49][17] = packed fp16 logit pairs (g,g+1);
// overlaid after softmax with packed w-pairs [25][33] = (w[2p],w[2p+1]) per g.
__global__ __launch_bounds__(256,8) void k2_fused(const float* __restrict__ ws,
                                                  const _Float16* __restrict__ x3h,
                                                  float* __restrict__ out)
{
  __shared__ uint_t lgw[4*840];         // 13440 B
  __shared__ int    gp_s[4*64];         // 1024 B
  __shared__ __align__(16) float ags[4*256];  // 4096 B

  int tid = threadIdx.x;
  int bid0 = blockIdx.x;
  int bid = (bid0 & 7)*392 + (bid0 >> 3);     // XCD-contiguous pixel spans
  int b = bid / 784; int rem = bid - b*784;
  int row = rem / 14, xs4 = rem - row*14;
  int wv = __builtin_amdgcn_readfirstlane(tid >> 6);
  int lane = tid & 63;
  int y = row, x = xs4*4 + wv;
  int pix = y*HW + x;

  const float* bnc  = ws + BNC_OFF;
  const uint_t* c1h = (const uint_t*)ws + CW1H_OFF;
  const uint_t* c2h = (const uint_t*)ws + CW2H_OFF;
  const float* cw2b = ws + CW2B_OFF;
  uint_t* wvbase = lgw + wv*840;

  // ---- phase 1: per-tap MLP (lane = tap), GEMMs via f16 dot2; packed logit write ----
  {
    int k = lane;
    int kk = k < 49 ? k : 48;
    int ki = kk / 7, kj = kk - ki*7;
    int gy = refl(y + ki - 3), gx = refl(x + kj - 3);
    int go = gy*HW + gx;
    gp_s[wv*64 + lane] = go;            // window offsets for phase 3 (all 64 lanes)

    const float*  x1p = ws + X1T_OFF + (size_t)(b*NPIX + pix)*16;   // uniform -> s_load
    const float4* x2p = (const float4*)(ws + X2T_OFF + (size_t)(b*NPIX + go)*16);
    float4 v0 = x2p[0], v1 = x2p[1], v2 = x2p[2], v3 = x2p[3];
    float x2v[16] = {v0.x,v0.y,v0.z,v0.w, v1.x,v1.y,v1.z,v1.w,
                     v2.x,v2.y,v2.z,v2.w, v3.x,v3.y,v3.z,v3.w};
    float h1[16];
    #pragma unroll
    for (int c=0;c<16;c++){
      float d = x1p[c] - x2v[c];
      h1[c] = fmaxf(d*bnc[c] + bnc[16+c], 0.f);
    }
    half2v hp[8];
    #pragma unroll
    for (int p=0;p<8;p++) hp[p] = __builtin_amdgcn_cvt_pkrtz(h1[2*p], h1[2*p+1]);

    float tt[16];
    #pragma unroll
    for (int o=0;o<16;o++){
      float a = 0.f;
      #pragma unroll
      for (int p=0;p<8;p++){
        union { uint_t u; half2v h; } cv; cv.u = c1h[o*8+p];
        a = __builtin_amdgcn_fdot2(hp[p], cv.h, a, false);
      }
      tt[o] = fmaxf(a*bnc[32+o] + bnc[48+o], 0.f);
    }
    half2v tp[8];
    #pragma unroll
    for (int p=0;p<8;p++) tp[p] = __builtin_amdgcn_cvt_pkrtz(tt[2*p], tt[2*p+1]);

    if (k < 49){
      #pragma unroll
      for (int gp=0; gp<16; gp++){
        float a0 = cw2b[2*gp], a1 = cw2b[2*gp+1];
        #pragma unroll
        for (int p=0;p<8;p++){
          union { uint_t u; half2v h; } e0, e1;
          e0.u = c2h[(2*gp)*8+p];
          e1.u = c2h[(2*gp+1)*8+p];
          a0 = __builtin_amdgcn_fdot2(tp[p], e0.h, a0, false);
          a1 = __builtin_amdgcn_fdot2(tp[p], e1.h, a1, false);
        }
        union { half2v h; uint_t u; } pk;
        pk.h = __builtin_amdgcn_cvt_pkrtz(a0, a1);
        wvbase[k*17 + gp] = pk.u;
      }
    }
  }

  // ---- phase 2: softmax over 49 taps (fp32 in regs); write packed w-pairs ----
  {
    int half = lane >> 5, g = lane & 31, gsel = g & 1, gp = g >> 1;
    float e[25];
    float M = -3.0e38f;
    #pragma unroll
    for (int i=0;i<25;i++){
      if (half == 0 || i < 24){
        uint_t u = wvbase[(half*25+i)*17 + gp];
        union { ushort_t s; __fp16 h; } cv;
        cv.s = gsel ? (ushort_t)(u>>16) : (ushort_t)(u & 0xffffu);
        e[i] = (float)cv.h;
        M = fmaxf(M, e[i]);
      }
    }
    M = fmaxf(M, __shfl_xor(M, 32, 64));
    float s = 0.f;
    #pragma unroll
    for (int i=0;i<25;i++){
      if (half == 0 || i < 24){
        e[i] = __expf(e[i] - M);
        s += e[i];
      }
    }
    s += __shfl_xor(s, 32, 64);
    float inv = 1.f / s;
    #pragma unroll
    for (int i=0;i<25;i++){
      if (half == 0 || i < 24) e[i] *= inv;
    }
    float other = __shfl_xor(half ? e[0] : e[24], 32, 64);  // half0 gets w25
    if (half == 0){
      #pragma unroll
      for (int p=0;p<12;p++){
        union { half2v h; uint_t u; } pk;
        pk.h = __builtin_amdgcn_cvt_pkrtz(e[2*p], e[2*p+1]);
        wvbase[p*33 + g] = pk.u;
      }
      union { half2v h; uint_t u; } pk;
      pk.h = __builtin_amdgcn_cvt_pkrtz(e[24], other);      // pair 12 = taps 24,25
      wvbase[12*33 + g] = pk.u;
    } else {
      #pragma unroll
      for (int q=0;q<11;q++){
        union { half2v h; uint_t u; } pk;
        pk.h = __builtin_amdgcn_cvt_pkrtz(e[1+2*q], e[2+2*q]);  // taps 26+2q,27+2q
        wvbase[(13+q)*33 + g] = pk.u;
      }
      union { half2v h; uint_t u; } pk;
      pk.h = __builtin_amdgcn_cvt_pkrtz(e[23], 0.f);        // pair 24 = taps 48,(49=0)
      wvbase[24*33 + g] = pk.u;
    }
  }

  // ---- phase 3: aggregation (lane owns channels 4L..4L+3), tap-pairs ----
  {
    int g_ = lane >> 1;
    int c0 = lane * 4;
    const int* gpp = gp_s + wv*64;
    float a0=0.f,a1=0.f,a2=0.f,a3=0.f;
    const _Float16* xb = x3h + (size_t)b*NPIX*256 + c0;
    #pragma unroll 5
    for (int p=0;p<25;p++){
      uint_t wu = wvbase[p*33 + g_];
      union { ushort_t s; __fp16 h; } wl, wh;
      wl.s = (ushort_t)(wu & 0xffffu); wh.s = (ushort_t)(wu >> 16);
      float w0 = (float)wl.h, w1 = (float)wh.h;
      int gp0 = gpp[2*p], gp1 = gpp[2*p+1];
      union { uint2 u; _Float16 h[4]; } d0, d1;
      d0.u = *(const uint2*)(xb + (size_t)gp0*256);
      d1.u = *(const uint2*)(xb + (size_t)gp1*256);
      a0 += w0*(float)d0.h[0] + w1*(float)d1.h[0];
      a1 += w0*(float)d0.h[1] + w1*(float)d1.h[1];
      a2 += w0*(float)d0.h[2] + w1*(float)d1.h[2];
      a3 += w0*(float)d0.h[3] + w1*(float)d1.h[3];
    }
    *(float4*)&ags[wv*256 + c0] = make_float4(a0,a1,a2,a3);
  }
  __syncthreads();

  // ---- phase 4: position2, block-wide (thread = out channel c, 4 px), tap-pairs ----
  {
    int c = tid, g4 = c >> 3;
    const float* P2 = ws + P2T_OFF;
    const uint_t* P2H = (const uint_t*)ws + P2H_OFF;
    float r0=0.f, r1=0.f, r2=0.f, r3=0.f;
    #pragma unroll
    for (int i=0;i<8;i++){
      float pv = P2[i*256 + c];
      r0 += ags[0*256 + i*32 + g4] * pv;
      r1 += ags[1*256 + i*32 + g4] * pv;
      r2 += ags[2*256 + i*32 + g4] * pv;
      r3 += ags[3*256 + i*32 + g4] * pv;
    }
    #pragma unroll 5
    for (int p=0;p<25;p++){
      union { uint_t u; half2v h; } ph; ph.u = P2H[p*256 + c];
      union { uint_t u; half2v h; } w0, w1, w2, w3;
      w0.u = lgw[0*840 + p*33 + g4];
      w1.u = lgw[1*840 + p*33 + g4];
      w2.u = lgw[2*840 + p*33 + g4];
      w3.u = lgw[3*840 + p*33 + g4];
      r0 = __builtin_amdgcn_fdot2(w0.h, ph.h, r0, false);
      r1 = __builtin_amdgcn_fdot2(w1.h, ph.h, r1, false);
      r2 = __builtin_amdgcn_fdot2(w2.h, ph.h, r2, false);
      r3 = __builtin_amdgcn_fdot2(w3.h, ph.h, r3, false);
    }
    int pix0 = y*HW + xs4*4;
    *(float4*)(out + ((size_t)(b*256 + c))*NPIX + pix0) = make_float4(r0,r1,r2,r3);
  }
}

// ===================== launch =====================
extern "C" void kernel_launch(void* const* d_in, const int* in_sizes, int n_in,
                              void* d_out, int out_size, void* d_ws, size_t ws_size,
                              hipStream_t stream) {
  const float* x    = (const float*)d_in[0];
  const float* w1   = (const float*)d_in[1];
  const float* b1   = (const float*)d_in[2];
  const float* w2   = (const float*)d_in[3];
  const float* b2   = (const float*)d_in[4];
  const float* w3   = (const float*)d_in[5];
  const float* b3   = (const float*)d_in[6];
  const float* g1   = (const float*)d_in[7];
  const float* be1  = (const float*)d_in[8];
  const float* m1   = (const float*)d_in[9];
  const float* v1   = (const float*)d_in[10];
  const float* cw1  = (const float*)d_in[11];
  const float* g2   = (const float*)d_in[12];
  const float* be2  = (const float*)d_in[13];
  const float* m2   = (const float*)d_in[14];
  const float* v2   = (const float*)d_in[15];
  const float* cw2  = (const float*)d_in[16];
  const float* cw2b = (const float*)d_in[17];
  const float* p2   = (const float*)d_in[18];

  float* wsf = (float*)d_ws;
  _Float16* x3h = (_Float16*)((char*)d_ws + X3_BYTE_OFF);
  float* o = (float*)d_out;

  k0_prep<<<481, 256, 0, stream>>>(w1,b1,w2,b2,w3,b3,g1,be1,m1,v1,cw1,g2,be2,m2,v2,cw2,cw2b,p2,wsf);
  k1_proj<<<196, 256, 0, stream>>>(x, wsf, x3h);
  k2_fused<<<3136, 256, 0, stream>>>(wsf, x3h, o);
}